// Round 2
// baseline (8719.200 us; speedup 1.0000x reference)
//
#include <hip/hip_runtime.h>
#include <hip/hip_bf16.h>
#include <math.h>

// Problem constants
#define BB   4
#define TT   16
#define HH   64
#define WW   64
#define CIN  64
#define CC   64    // C_OUT
#define CO4  256   // 4*C_OUT
#define BN_EPS 1e-3f

// ---------------------------------------------------------------------------
// Workspace layout (fp32 baseline):
//   h_pad : [B][66][66][64] fp32 (zero-padded h state)   = 4,460,544 B
//   c_st  : [B][64][64][64] fp32                         = 4,194,304 B
//   z     : [B][64][64][256] fp32 (per-timestep gates)   = 16,777,216 B
// h_pad + c_st are zeroed once per launch via hipMemsetAsync.
// ---------------------------------------------------------------------------
#define HPAD_ELEMS (BB * 66 * 66 * CC)            // 1,115,136
#define CST_ELEMS  (BB * HH * WW * CC)            // 1,048,576
#define HPAD_BYTES (HPAD_ELEMS * 4)
#define CST_BYTES  (CST_ELEMS * 4)
#define Z_OFFSET_BYTES (HPAD_BYTES + CST_BYTES)   // 8,654,848

// ---------------------------------------------------------------------------
// conv_z: z[b][y][x][co] = bias[co]
//           + sum_{kh,kw,ci} x_t[b][y+kh-1][x+kw-1][ci] * W[kh][kw][ci][co]
//           + sum_{kh,kw,ci} h  [b][y+kh-1][x+kw-1][ci] * U[kh][kw][ci][co]
// Grid: 1024 blocks = b(4) x tile(8x8 of 8x8 pixels -> 64) x co-quarter(4)
// Block: 256 threads = 64 pixels x 4 groups; each group handles 16 co.
// ---------------------------------------------------------------------------
__global__ __launch_bounds__(256) void conv_z_kernel(
    const float* __restrict__ x,      // [4,16,64,64,64]
    const float* __restrict__ Wt,     // [3,3,64,256]
    const float* __restrict__ Ut,     // [3,3,64,256]
    const float* __restrict__ bias,   // [256]
    const float* __restrict__ h_pad,  // [4,66,66,64]
    float* __restrict__ z,            // [4,64,64,256]
    int t)
{
    // LDS input tile: [ci 32][yy 10][xx 10], x-stride padded to 12
    __shared__ float tile[32 * 10 * 12];

    const int blk  = blockIdx.x;
    const int coq  = blk & 3;                 // which 64-wide co quarter
    const int tIdx = (blk >> 2) & 63;         // spatial tile
    const int b    = blk >> 8;
    const int y0   = (tIdx >> 3) * 8;
    const int x0   = (tIdx & 7) * 8;

    const int tid  = threadIdx.x;
    const int px   = tid & 63;                // pixel within 8x8 tile
    const int grp  = tid >> 6;                // 0..3 -> 16 co each
    const int py   = px >> 3;
    const int pxx  = px & 7;
    const int co_base = coq * 64 + grp * 16;  // first of 16 output channels

    const int xbase = (b * TT + t) * (HH * WW * CIN);
    const int hbase = b * (66 * 66 * CC);

    float acc[16];
#pragma unroll
    for (int i = 0; i < 16; ++i) acc[i] = bias[co_base + i];

    for (int src = 0; src < 2; ++src) {
        const float* wsrc = (src == 0) ? Wt : Ut;
        for (int ci0 = 0; ci0 < CIN; ci0 += 32) {
            __syncthreads();   // previous chunk's compute done before restage
            // ---- stage input tile (32 ci) x (10x10 spatial with halo) ----
            for (int idx = tid; idx < 3200; idx += 256) {
                int ci  = idx / 100;
                int rem = idx - ci * 100;
                int yy  = rem / 10;
                int xx  = rem - yy * 10;
                int gy  = y0 + yy - 1;
                int gx  = x0 + xx - 1;
                float v;
                if (src == 0) {
                    v = (gy >= 0 && gy < HH && gx >= 0 && gx < WW)
                            ? x[xbase + (gy * WW + gx) * CIN + ci0 + ci]
                            : 0.0f;
                } else {
                    // h_pad has the zero border built in
                    v = h_pad[hbase + ((gy + 1) * 66 + (gx + 1)) * CC + ci0 + ci];
                }
                tile[ci * 120 + yy * 12 + xx] = v;
            }
            __syncthreads();

            // ---- accumulate 9 taps x 32 ci for 16 output channels ----
            for (int kh = 0; kh < 3; ++kh) {
                for (int kw = 0; kw < 3; ++kw) {
                    const float* wp = wsrc + (((kh * 3 + kw) * CIN) + ci0) * CO4 + co_base;
                    const float* tp = tile + (py + kh) * 12 + (pxx + kw);
#pragma unroll 2
                    for (int ci = 0; ci < 32; ++ci) {
                        float a = tp[ci * 120];
                        const float4* w4 = (const float4*)(wp + ci * CO4);
                        float4 w0 = w4[0];
                        float4 w1 = w4[1];
                        float4 w2 = w4[2];
                        float4 w3 = w4[3];
                        acc[0]  = fmaf(a, w0.x, acc[0]);
                        acc[1]  = fmaf(a, w0.y, acc[1]);
                        acc[2]  = fmaf(a, w0.z, acc[2]);
                        acc[3]  = fmaf(a, w0.w, acc[3]);
                        acc[4]  = fmaf(a, w1.x, acc[4]);
                        acc[5]  = fmaf(a, w1.y, acc[5]);
                        acc[6]  = fmaf(a, w1.z, acc[6]);
                        acc[7]  = fmaf(a, w1.w, acc[7]);
                        acc[8]  = fmaf(a, w2.x, acc[8]);
                        acc[9]  = fmaf(a, w2.y, acc[9]);
                        acc[10] = fmaf(a, w2.z, acc[10]);
                        acc[11] = fmaf(a, w2.w, acc[11]);
                        acc[12] = fmaf(a, w3.x, acc[12]);
                        acc[13] = fmaf(a, w3.y, acc[13]);
                        acc[14] = fmaf(a, w3.z, acc[14]);
                        acc[15] = fmaf(a, w3.w, acc[15]);
                    }
                }
            }
        }
    }

    // ---- write z (16 consecutive co as 4x float4) ----
    const int y  = y0 + py;
    const int xg = x0 + pxx;
    float* zp = z + ((b * HH + y) * WW + xg) * CO4 + co_base;
    float4* zp4 = (float4*)zp;
#pragma unroll
    for (int i = 0; i < 4; ++i) {
        float4 v;
        v.x = acc[i * 4 + 0];
        v.y = acc[i * 4 + 1];
        v.z = acc[i * 4 + 2];
        v.w = acc[i * 4 + 3];
        zp4[i] = v;
    }
}

// ---------------------------------------------------------------------------
// gate_pool: per output pool cell (b, py, px, c):
//   for 4 pixels of the 2x2 window: gates -> c_new, h; BN; max-pool -> out.
// Also writes h into h_pad for the next timestep's recurrent conv.
// Grid: 1024 blocks x 256 threads = 262,144 = 4*32*32*64
// ---------------------------------------------------------------------------
__device__ __forceinline__ float hsig(float v) {
    return fminf(fmaxf(0.2f * v + 0.5f, 0.0f), 1.0f);
}

__global__ __launch_bounds__(256) void gate_pool_kernel(
    const float* __restrict__ z,       // [4,64,64,256]
    float* __restrict__ c_state,       // [4,64,64,64]
    float* __restrict__ h_pad,         // [4,66,66,64]
    float* __restrict__ out,           // [4,16,32,32,64]
    const float* __restrict__ gamma,
    const float* __restrict__ beta,
    const float* __restrict__ mean,
    const float* __restrict__ var,
    int t)
{
    const int idx = blockIdx.x * 256 + threadIdx.x;
    const int c   = idx & 63;
    const int pxy = idx >> 6;
    const int px  = pxy & 31;
    const int py  = (pxy >> 5) & 31;
    const int b   = pxy >> 10;

    const float scale = gamma[c] * rsqrtf(var[c] + BN_EPS);
    const float bns   = beta[c] - mean[c] * scale;

    float m = -INFINITY;
#pragma unroll
    for (int dy = 0; dy < 2; ++dy) {
#pragma unroll
        for (int dx = 0; dx < 2; ++dx) {
            const int y  = py * 2 + dy;
            const int xg = px * 2 + dx;
            const int zoff = ((b * HH + y) * WW + xg) * CO4;
            const float zi = z[zoff + c];
            const float zf = z[zoff + 64 + c];
            const float zg = z[zoff + 128 + c];
            const float zo = z[zoff + 192 + c];

            const float gi = hsig(zi);
            const float gf = hsig(zf);
            const float gg = tanhf(zg);
            const float go = hsig(zo);

            const int coff = ((b * HH + y) * WW + xg) * CC + c;
            const float cn = gf * c_state[coff] + gi * gg;
            c_state[coff]  = cn;
            const float h  = go * tanhf(cn);

            h_pad[((b * 66 + (y + 1)) * 66 + (xg + 1)) * CC + c] = h;

            m = fmaxf(m, h * scale + bns);
        }
    }
    out[(((b * TT + t) * 32 + py) * 32 + px) * CC + c] = m;
}

// ---------------------------------------------------------------------------
extern "C" void kernel_launch(void* const* d_in, const int* in_sizes, int n_in,
                              void* d_out, int out_size, void* d_ws, size_t ws_size,
                              hipStream_t stream) {
    const float* x     = (const float*)d_in[0];
    const float* Wt    = (const float*)d_in[1];
    const float* Ut    = (const float*)d_in[2];
    const float* bias  = (const float*)d_in[3];
    const float* gamma = (const float*)d_in[4];
    const float* beta  = (const float*)d_in[5];
    const float* mean  = (const float*)d_in[6];
    const float* var   = (const float*)d_in[7];

    float* out = (float*)d_out;

    char* ws      = (char*)d_ws;
    float* h_pad  = (float*)ws;
    float* c_st   = (float*)(ws + HPAD_BYTES);
    float* z      = (float*)(ws + Z_OFFSET_BYTES);

    // zero h state (incl. pad border) and cell state
    hipMemsetAsync(d_ws, 0, (size_t)Z_OFFSET_BYTES, stream);

    for (int t = 0; t < TT; ++t) {
        conv_z_kernel<<<dim3(1024), dim3(256), 0, stream>>>(
            x, Wt, Ut, bias, h_pad, z, t);
        gate_pool_kernel<<<dim3(1024), dim3(256), 0, stream>>>(
            z, c_st, h_pad, out, gamma, beta, mean, var, t);
    }
}

// Round 3
// 635.600 us; speedup vs baseline: 13.7181x; 13.7181x over previous
//
#include <hip/hip_runtime.h>
#include <hip/hip_fp16.h>
#include <math.h>

// Problem constants
#define BB   4
#define TT   16
#define HH   64
#define WW   64
#define CC   64    // C_OUT
#define CO4  256   // 4*C_OUT
#define BN_EPS 1e-3f

typedef _Float16 f16;
typedef f16  f16x8 __attribute__((ext_vector_type(8)));
typedef float f32x4 __attribute__((ext_vector_type(4)));

// ---------------------------------------------------------------------------
// Workspace layout:
//   in_pad : [4][66][66][128] f16  (ch 0-63 = x_t, ch 64-127 = h; zero border)
//   c_st   : [4][64][64][64] f32
//   z      : [4][64][64][256] f32
//   wt     : [256][1152] f16  (K order: tap*128 + ci; ci<64 -> W, ci>=64 -> U)
// ---------------------------------------------------------------------------
#define INPAD_BYTES (BB * 66 * 66 * 128 * 2)          // 4,460,544
#define CST_BYTES   (BB * 64 * 64 * 64 * 4)           // 4,194,304
#define Z_BYTES     (BB * 64 * 64 * 256 * 4)          // 16,777,216
#define OFF_CST   INPAD_BYTES
#define OFF_Z     (INPAD_BYTES + CST_BYTES)
#define OFF_WT    (OFF_Z + Z_BYTES)                   // 25,432,064

// ---------------------------------------------------------------------------
// prep_wt: Wt[n][k] = f16( k%128 < 64 ? W[kh][kw][ci][n] : U[kh][kw][ci-64][n] )
// ---------------------------------------------------------------------------
__global__ __launch_bounds__(256) void prep_wt_kernel(
    const float* __restrict__ W, const float* __restrict__ U,
    f16* __restrict__ wt)
{
    int idx = blockIdx.x * 256 + threadIdx.x;   // 256*1152 = 294,912
    if (idx >= 256 * 1152) return;
    int n = idx / 1152;
    int k = idx - n * 1152;
    int tap = k >> 7;          // 0..8  (kh*3+kw)
    int ci  = k & 127;
    float v = (ci < 64) ? W[(tap * 64 + ci) * 256 + n]
                        : U[(tap * 64 + (ci - 64)) * 256 + n];
    wt[idx] = (f16)v;
}

// ---------------------------------------------------------------------------
// convert_x0: x[:,0] -> in_pad x-channels
// ---------------------------------------------------------------------------
__global__ __launch_bounds__(256) void convert_x0_kernel(
    const float* __restrict__ x, f16* __restrict__ in_pad)
{
    int idx = blockIdx.x * 256 + threadIdx.x;   // 4*64*64*64 = 1,048,576
    int c  = idx & 63;
    int xx = (idx >> 6) & 63;
    int yy = (idx >> 12) & 63;
    int b  = idx >> 18;
    float v = x[(((b * TT + 0) * HH + yy) * WW + xx) * 64 + c];
    in_pad[((b * 66 + yy + 1) * 66 + (xx + 1)) * 128 + c] = (f16)v;
}

// ---------------------------------------------------------------------------
// conv_z_mfma: implicit GEMM, M=64px/block (8x8 tile), N=256, K=1152.
// Block 256 thr = 4 waves; wave w covers 64px x 64ch (4x4 reps of 16x16x32).
// A LDS: [100 px][136 f16] (272B stride: 8 banks x2-way = conflict-free)
// B LDS: 2 x [256 n][40 f16] (80B stride: 8 banks x2-way = conflict-free)
// ---------------------------------------------------------------------------
#define A_LDS_BYTES (100 * 272)          // 27,200
#define B_LDS_BYTES (256 * 80)           // 20,480

__global__ __launch_bounds__(256) void conv_z_mfma(
    const f16* __restrict__ in_pad, const f16* __restrict__ wt,
    const float* __restrict__ bias, float* __restrict__ z)
{
    __shared__ char lds[A_LDS_BYTES + 2 * B_LDS_BYTES];   // 68,160 B
    char* As  = lds;
    char* Bs0 = lds + A_LDS_BYTES;
    char* Bs1 = lds + A_LDS_BYTES + B_LDS_BYTES;

    const int blk = blockIdx.x;              // b*64 + ty*8 + tx
    const int tx  = blk & 7;
    const int ty  = (blk >> 3) & 7;
    const int b   = blk >> 6;
    const int tid = threadIdx.x;
    const int w   = tid >> 6;                // wave -> 64-ch quarter
    const int l   = tid & 63;
    const int l15 = l & 15;
    const int lk  = l >> 4;                  // k-octet group (0..3)

    // ---- stage A: 10x10 px halo x 128 ci (1600 x 16B chunks) ----
    {
        const f16* src = in_pad + ((b * 66 + ty * 8) * 66 + tx * 8) * 128;
        for (int r = 0; r < 7; ++r) {
            int flat = r * 256 + tid;
            if (flat < 1600) {
                int pxi = flat >> 4;                   // pixel index 0..99
                int oct = flat & 15;                   // ci octet
                int ly  = pxi / 10;
                int lx  = pxi - ly * 10;
                uint4 v = *(const uint4*)(src + (ly * 66 + lx) * 128 + oct * 8);
                *(uint4*)(As + pxi * 272 + oct * 16) = v;
            }
        }
    }

    // ---- B staging helpers (reg-staged; 4 x 16B per thread per chunk) ----
    uint4 pre0, pre1, pre2, pre3;
    #define STAGE_B_LOAD(ks) do {                                          \
        const f16* _src = wt + (ks) * 32;                                  \
        pre0 = *(const uint4*)(_src + ((0*256 + tid) >> 2) * 1152 + (tid & 3) * 8); \
        pre1 = *(const uint4*)(_src + ((1*256 + tid) >> 2) * 1152 + (tid & 3) * 8); \
        pre2 = *(const uint4*)(_src + ((2*256 + tid) >> 2) * 1152 + (tid & 3) * 8); \
        pre3 = *(const uint4*)(_src + ((3*256 + tid) >> 2) * 1152 + (tid & 3) * 8); \
    } while (0)
    #define STAGE_B_WRITE(dst) do {                                        \
        *(uint4*)((dst) + ((0*256 + tid) >> 2) * 80 + (tid & 3) * 16) = pre0; \
        *(uint4*)((dst) + ((1*256 + tid) >> 2) * 80 + (tid & 3) * 16) = pre1; \
        *(uint4*)((dst) + ((2*256 + tid) >> 2) * 80 + (tid & 3) * 16) = pre2; \
        *(uint4*)((dst) + ((3*256 + tid) >> 2) * 80 + (tid & 3) * 16) = pre3; \
    } while (0)

    STAGE_B_LOAD(0);
    STAGE_B_WRITE(Bs0);

    // ---- accumulators: init with bias (C layout: col=l&15 -> n) ----
    f32x4 acc[4][4];
    #pragma unroll
    for (int nr = 0; nr < 4; ++nr) {
        float bv = bias[w * 64 + nr * 16 + l15];
        #pragma unroll
        for (int mr = 0; mr < 4; ++mr) {
            acc[mr][nr][0] = bv; acc[mr][nr][1] = bv;
            acc[mr][nr][2] = bv; acc[mr][nr][3] = bv;
        }
    }

    __syncthreads();

    // ---- K loop: 36 chunks of 32 (tap = ks>>2, ci-quarter = ks&3) ----
    for (int ks = 0; ks < 36; ++ks) {
        if (ks < 35) STAGE_B_LOAD(ks + 1);

        const char* Bcur = (ks & 1) ? Bs1 : Bs0;
        const int tap = ks >> 2;
        const int kh  = tap / 3;
        const int kw  = tap - kh * 3;
        const int cq  = ks & 3;

        f16x8 af[4], bf[4];
        #pragma unroll
        for (int mr = 0; mr < 4; ++mr) {
            int p   = mr * 16 + l15;
            int pix = ((p >> 3) + kh) * 10 + (p & 7) + kw;
            af[mr] = *(const f16x8*)(As + pix * 272 + cq * 64 + lk * 16);
        }
        #pragma unroll
        for (int nr = 0; nr < 4; ++nr) {
            int n = w * 64 + nr * 16 + l15;
            bf[nr] = *(const f16x8*)(Bcur + n * 80 + lk * 16);
        }
        #pragma unroll
        for (int mr = 0; mr < 4; ++mr)
            #pragma unroll
            for (int nr = 0; nr < 4; ++nr)
                acc[mr][nr] = __builtin_amdgcn_mfma_f32_16x16x32_f16(
                    af[mr], bf[nr], acc[mr][nr], 0, 0, 0);

        if (ks < 35) STAGE_B_WRITE((ks & 1) ? Bs0 : Bs1);
        __syncthreads();
    }

    // ---- epilogue: write z (fp32). C row = (l>>4)*4+reg -> pixel ----
    const int y0 = ty * 8, x0 = tx * 8;
    #pragma unroll
    for (int mr = 0; mr < 4; ++mr) {
        #pragma unroll
        for (int reg = 0; reg < 4; ++reg) {
            int p  = mr * 16 + lk * 4 + reg;
            int y  = y0 + (p >> 3);
            int xx = x0 + (p & 7);
            float* zp = z + ((b * HH + y) * WW + xx) * CO4 + w * 64 + l15;
            #pragma unroll
            for (int nr = 0; nr < 4; ++nr)
                zp[nr * 16] = acc[mr][nr][reg];
        }
    }
}

// ---------------------------------------------------------------------------
// gate_pool: gates -> c_new, h; h (f16) + x_{t+1} (f16) into in_pad; BN; pool.
// ---------------------------------------------------------------------------
__device__ __forceinline__ float hsig(float v) {
    return fminf(fmaxf(0.2f * v + 0.5f, 0.0f), 1.0f);
}

__global__ __launch_bounds__(256) void gate_pool_kernel(
    const float* __restrict__ z,       // [4,64,64,256]
    const float* __restrict__ x,       // [4,16,64,64,64]
    float* __restrict__ c_state,       // [4,64,64,64]
    f16*   __restrict__ in_pad,        // [4,66,66,128]
    float* __restrict__ out,           // [4,16,32,32,64]
    const float* __restrict__ gamma,
    const float* __restrict__ beta,
    const float* __restrict__ mean,
    const float* __restrict__ var,
    int t)
{
    const int idx = blockIdx.x * 256 + threadIdx.x;
    const int c   = idx & 63;
    const int px  = (idx >> 6) & 31;
    const int py  = (idx >> 11) & 31;
    const int b   = idx >> 16;

    const float scale = gamma[c] * rsqrtf(var[c] + BN_EPS);
    const float bns   = beta[c] - mean[c] * scale;

    float m = -INFINITY;
#pragma unroll
    for (int dy = 0; dy < 2; ++dy) {
#pragma unroll
        for (int dx = 0; dx < 2; ++dx) {
            const int y  = py * 2 + dy;
            const int xg = px * 2 + dx;
            const int zoff = ((b * HH + y) * WW + xg) * CO4;
            const float zi = z[zoff + c];
            const float zf = z[zoff + 64 + c];
            const float zg = z[zoff + 128 + c];
            const float zo = z[zoff + 192 + c];

            const float gi = hsig(zi);
            const float gf = hsig(zf);
            const float gg = tanhf(zg);
            const float go = hsig(zo);

            const int coff = ((b * HH + y) * WW + xg) * CC + c;
            const float cn = gf * c_state[coff] + gi * gg;
            c_state[coff]  = cn;
            const float h  = go * tanhf(cn);

            f16* pp = in_pad + ((b * 66 + (y + 1)) * 66 + (xg + 1)) * 128;
            pp[64 + c] = (f16)h;
            if (t + 1 < TT)
                pp[c] = (f16)x[(((b * TT + t + 1) * HH + y) * WW + xg) * 64 + c];

            m = fmaxf(m, h * scale + bns);
        }
    }
    out[(((b * TT + t) * 32 + py) * 32 + px) * CC + c] = m;
}

// ---------------------------------------------------------------------------
extern "C" void kernel_launch(void* const* d_in, const int* in_sizes, int n_in,
                              void* d_out, int out_size, void* d_ws, size_t ws_size,
                              hipStream_t stream) {
    const float* x     = (const float*)d_in[0];
    const float* W     = (const float*)d_in[1];
    const float* U     = (const float*)d_in[2];
    const float* bias  = (const float*)d_in[3];
    const float* gamma = (const float*)d_in[4];
    const float* beta  = (const float*)d_in[5];
    const float* mean  = (const float*)d_in[6];
    const float* var   = (const float*)d_in[7];

    float* out = (float*)d_out;

    char*  ws     = (char*)d_ws;
    f16*   in_pad = (f16*)ws;
    float* c_st   = (float*)(ws + OFF_CST);
    float* z      = (float*)(ws + OFF_Z);
    f16*   wt     = (f16*)(ws + OFF_WT);

    // zero in_pad (incl. borders + h channels) and c_state
    hipMemsetAsync(d_ws, 0, (size_t)OFF_Z, stream);
    prep_wt_kernel<<<dim3(1152), dim3(256), 0, stream>>>(W, U, wt);
    convert_x0_kernel<<<dim3(4096), dim3(256), 0, stream>>>(x, in_pad);

    for (int t = 0; t < TT; ++t) {
        conv_z_mfma<<<dim3(256), dim3(256), 0, stream>>>(in_pad, wt, bias, z);
        gate_pool_kernel<<<dim3(1024), dim3(256), 0, stream>>>(
            z, x, c_st, in_pad, out, gamma, beta, mean, var, t);
    }
}

// Round 4
// 585.699 us; speedup vs baseline: 14.8868x; 1.0852x over previous
//
#include <hip/hip_runtime.h>
#include <hip/hip_fp16.h>
#include <math.h>

// Problem constants
#define BB   4
#define TT   16
#define HH   64
#define WW   64
#define CC   64
#define CO4  256
#define BN_EPS 1e-3f

typedef _Float16 f16;
typedef f16  f16x8 __attribute__((ext_vector_type(8)));
typedef float f32x4 __attribute__((ext_vector_type(4)));

// ---------------------------------------------------------------------------
// Workspace layout (ws_size = 256 MiB):
//   hp0,hp1 : 2 x [4][66][66][64] f16   (double-buffered padded h state)
//   c_st    : [4][64][64][64] f32
//   x16     : [4][16][64][64][64] f16   (x converted once)
//   wt_x    : [256 n][576 k] f16        (k = tap*64+ci, from W)
//   wt_h    : [256 n][576 k] f16        (from U)
//   zx      : [64 frames][4096 px][256 n] f16  (x-conv + bias, all timesteps)
// ---------------------------------------------------------------------------
#define HPAD_BYTES (BB * 66 * 66 * 64 * 2)     // 2,230,272
#define CST_BYTES  (BB * 64 * 64 * 64 * 4)     // 4,194,304
#define X16_BYTES  (BB * TT * 64 * 64 * 64 * 2)// 33,554,432
#define WT_BYTES   (256 * 576 * 2)             // 294,912
#define OFF_HP1  HPAD_BYTES
#define OFF_CST  (2 * HPAD_BYTES)              // 4,460,544
#define OFF_X16  (OFF_CST + CST_BYTES)         // 8,654,848
#define OFF_WTX  (OFF_X16 + X16_BYTES)         // 42,209,280
#define OFF_WTH  (OFF_WTX + WT_BYTES)          // 42,504,192
#define OFF_ZX   (OFF_WTH + WT_BYTES)          // 42,799,104 (+134,217,728)

// ---------------------------------------------------------------------------
__global__ __launch_bounds__(256) void prep_wt_kernel(
    const float* __restrict__ W, const float* __restrict__ U,
    f16* __restrict__ wtx, f16* __restrict__ wth)
{
    int idx = blockIdx.x * 256 + threadIdx.x;   // 256*576 = 147,456... grid 1152*256 = 294,912? No: 576 blocks
    if (idx >= 256 * 576) return;
    int n = idx / 576;
    int k = idx - n * 576;
    int tap = k >> 6;          // 0..8
    int ci  = k & 63;
    wtx[idx] = (f16)W[(tap * 64 + ci) * 256 + n];
    wth[idx] = (f16)U[(tap * 64 + ci) * 256 + n];
}

__global__ __launch_bounds__(256) void convert_x_kernel(
    const float* __restrict__ x, f16* __restrict__ x16)
{
    int idx = blockIdx.x * 256 + threadIdx.x;   // 2,097,152 threads x 8 elems
    const float4* s = (const float4*)x + idx * 2;
    float4 a = s[0], b = s[1];
    f16x8 v;
    v[0] = (f16)a.x; v[1] = (f16)a.y; v[2] = (f16)a.z; v[3] = (f16)a.w;
    v[4] = (f16)b.x; v[5] = (f16)b.y; v[6] = (f16)b.z; v[7] = (f16)b.w;
    *(f16x8*)(x16 + idx * 8) = v;
}

// ---------------------------------------------------------------------------
// zx_gemm: zx[f][px][n] = bias[n] + conv(x_f, W)[px][n]   (f16 out)
// Grid 4096 = 64 frames x 64 tiles(8x8 px). 4 waves; wave = 64px x 64n.
// ---------------------------------------------------------------------------
#define A_BYTES (100 * 144)        // 14,400  ([100 px][72 f16] padded)
#define B_BYTES (256 * 80)         // 20,480  ([256 n][40 f16] padded)

__global__ __launch_bounds__(256) void zx_gemm(
    const f16* __restrict__ x16, const f16* __restrict__ wtx,
    const float* __restrict__ bias, f16* __restrict__ zx)
{
    __shared__ char lds[A_BYTES + 2 * B_BYTES];    // 55,360
    char* As  = lds;
    char* Bs0 = lds + A_BYTES;
    char* Bs1 = Bs0 + B_BYTES;

    const int blk = blockIdx.x;
    const int f   = blk >> 6;
    const int tIdx = blk & 63;
    const int y0 = (tIdx >> 3) * 8, x0 = (tIdx & 7) * 8;
    const int tid = threadIdx.x;
    const int w = tid >> 6, l = tid & 63, l15 = l & 15, lk = l >> 4;

    // stage A: 10x10 halo x 64 ci, bounds-checked (800 x 16B)
    const f16* fb = x16 + f * (4096 * 64);
    for (int r = 0; r < 4; ++r) {
        int flat = r * 256 + tid;
        if (flat < 800) {
            int pxi = flat >> 3, oct = flat & 7;
            int ly = pxi / 10, lx = pxi - ly * 10;
            int gy = y0 + ly - 1, gx = x0 + lx - 1;
            uint4 v = {0u, 0u, 0u, 0u};
            if (gy >= 0 && gy < 64 && gx >= 0 && gx < 64)
                v = *(const uint4*)(fb + (gy * 64 + gx) * 64 + oct * 8);
            *(uint4*)(As + pxi * 144 + oct * 16) = v;
        }
    }

    uint4 pre0, pre1, pre2, pre3;
#define BLOAD(src, ks) do {                                                   \
        const f16* _s = (src) + (ks) * 32 + (tid & 3) * 8;                    \
        pre0 = *(const uint4*)(_s + (((0*256 + tid) >> 2) * 576));            \
        pre1 = *(const uint4*)(_s + (((1*256 + tid) >> 2) * 576));            \
        pre2 = *(const uint4*)(_s + (((2*256 + tid) >> 2) * 576));            \
        pre3 = *(const uint4*)(_s + (((3*256 + tid) >> 2) * 576));            \
    } while (0)
#define BWRITE(dst) do {                                                      \
        *(uint4*)((dst) + ((0*256 + tid) >> 2) * 80 + (tid & 3) * 16) = pre0; \
        *(uint4*)((dst) + ((1*256 + tid) >> 2) * 80 + (tid & 3) * 16) = pre1; \
        *(uint4*)((dst) + ((2*256 + tid) >> 2) * 80 + (tid & 3) * 16) = pre2; \
        *(uint4*)((dst) + ((3*256 + tid) >> 2) * 80 + (tid & 3) * 16) = pre3; \
    } while (0)

    BLOAD(wtx, 0);
    BWRITE(Bs0);

    f32x4 acc[4][4];
#pragma unroll
    for (int nr = 0; nr < 4; ++nr) {
        float bv = bias[w * 64 + nr * 16 + l15];
#pragma unroll
        for (int mr = 0; mr < 4; ++mr) {
            acc[mr][nr][0] = bv; acc[mr][nr][1] = bv;
            acc[mr][nr][2] = bv; acc[mr][nr][3] = bv;
        }
    }
    __syncthreads();

    for (int ks = 0; ks < 18; ++ks) {
        if (ks < 17) BLOAD(wtx, ks + 1);
        const char* Bcur = (ks & 1) ? Bs1 : Bs0;
        const int tap = ks >> 1, cq = ks & 1;
        const int kh = tap / 3, kw = tap - kh * 3;

        f16x8 af[4], bf[4];
#pragma unroll
        for (int mr = 0; mr < 4; ++mr) {
            int p = mr * 16 + l15;
            int pix = ((p >> 3) + kh) * 10 + (p & 7) + kw;
            af[mr] = *(const f16x8*)(As + pix * 144 + cq * 64 + lk * 16);
        }
#pragma unroll
        for (int nr = 0; nr < 4; ++nr)
            bf[nr] = *(const f16x8*)(Bcur + (w * 64 + nr * 16 + l15) * 80 + lk * 16);
#pragma unroll
        for (int mr = 0; mr < 4; ++mr)
#pragma unroll
            for (int nr = 0; nr < 4; ++nr)
                acc[mr][nr] = __builtin_amdgcn_mfma_f32_16x16x32_f16(
                    af[mr], bf[nr], acc[mr][nr], 0, 0, 0);

        if (ks < 17) BWRITE((ks & 1) ? Bs0 : Bs1);
        __syncthreads();
    }

    // epilogue: f16 store
    f16* zb = zx + (size_t)f * (4096 * 256);
#pragma unroll
    for (int mr = 0; mr < 4; ++mr)
#pragma unroll
        for (int reg = 0; reg < 4; ++reg) {
            int p = mr * 16 + lk * 4 + reg;
            int pxg = (y0 + (p >> 3)) * 64 + x0 + (p & 7);
#pragma unroll
            for (int nr = 0; nr < 4; ++nr)
                zb[pxg * 256 + w * 64 + nr * 16 + l15] = (f16)acc[mr][nr][reg];
        }
}

// ---------------------------------------------------------------------------
// step_fused: z = zx_t + conv(h, U); gates; c,h update; BN; 2x2 maxpool.
// Grid 256 = b(4) x 64 tiles. LDS reused: conv (A+B) then z-exchange.
// ---------------------------------------------------------------------------
#define ZL_STRIDE 260                       // f32, pad 4
#define ZL_BYTES  (64 * ZL_STRIDE * 4)      // 66,560

__device__ __forceinline__ float hsig(float v) {
    return fminf(fmaxf(0.2f * v + 0.5f, 0.0f), 1.0f);
}

__global__ __launch_bounds__(256) void step_fused(
    const f16* __restrict__ hp_in,   // [4][66][66][64]
    f16* __restrict__ hp_out,
    const f16* __restrict__ wth,
    const f16* __restrict__ zx,      // [64][4096][256]
    float* __restrict__ c_st,        // [4][64][64][64]
    float* __restrict__ out,         // [4][16][32][32][64]
    const float* __restrict__ gamma, const float* __restrict__ beta,
    const float* __restrict__ mean,  const float* __restrict__ var,
    int t)
{
    __shared__ char lds[ZL_BYTES];           // >= A_BYTES + 2*B_BYTES
    char* As  = lds;
    char* Bs0 = lds + A_BYTES;
    char* Bs1 = Bs0 + B_BYTES;

    const int blk = blockIdx.x;
    const int b   = blk >> 6;
    const int tIdx = blk & 63;
    const int ty = tIdx >> 3, tx = tIdx & 7;
    const int y0 = ty * 8, x0 = tx * 8;
    const int tid = threadIdx.x;
    const int w = tid >> 6, l = tid & 63, l15 = l & 15, lk = l >> 4;

    // stage A from padded h (no bounds check)
    const f16* hb = hp_in + b * (66 * 66 * 64);
    for (int r = 0; r < 4; ++r) {
        int flat = r * 256 + tid;
        if (flat < 800) {
            int pxi = flat >> 3, oct = flat & 7;
            int ly = pxi / 10, lx = pxi - ly * 10;
            uint4 v = *(const uint4*)(hb + ((y0 + ly) * 66 + x0 + lx) * 64 + oct * 8);
            *(uint4*)(As + pxi * 144 + oct * 16) = v;
        }
    }

    uint4 pre0, pre1, pre2, pre3;
    BLOAD(wth, 0);
    BWRITE(Bs0);

    f32x4 acc[4][4];
#pragma unroll
    for (int mr = 0; mr < 4; ++mr)
#pragma unroll
        for (int nr = 0; nr < 4; ++nr)
            acc[mr][nr] = (f32x4){0.f, 0.f, 0.f, 0.f};
    __syncthreads();

    for (int ks = 0; ks < 18; ++ks) {
        if (ks < 17) BLOAD(wth, ks + 1);
        const char* Bcur = (ks & 1) ? Bs1 : Bs0;
        const int tap = ks >> 1, cq = ks & 1;
        const int kh = tap / 3, kw = tap - kh * 3;

        f16x8 af[4], bf[4];
#pragma unroll
        for (int mr = 0; mr < 4; ++mr) {
            int p = mr * 16 + l15;
            int pix = ((p >> 3) + kh) * 10 + (p & 7) + kw;
            af[mr] = *(const f16x8*)(As + pix * 144 + cq * 64 + lk * 16);
        }
#pragma unroll
        for (int nr = 0; nr < 4; ++nr)
            bf[nr] = *(const f16x8*)(Bcur + (w * 64 + nr * 16 + l15) * 80 + lk * 16);
#pragma unroll
        for (int mr = 0; mr < 4; ++mr)
#pragma unroll
            for (int nr = 0; nr < 4; ++nr)
                acc[mr][nr] = __builtin_amdgcn_mfma_f32_16x16x32_f16(
                    af[mr], bf[nr], acc[mr][nr], 0, 0, 0);

        if (ks < 17) BWRITE((ks & 1) ? Bs0 : Bs1);
        __syncthreads();
    }

    // add zx, exchange z through LDS
    const f16* zxb = zx + ((size_t)(b * TT + t) * 4096) * 256;
    float* zl = (float*)lds;
#pragma unroll
    for (int mr = 0; mr < 4; ++mr)
#pragma unroll
        for (int reg = 0; reg < 4; ++reg) {
            int p = mr * 16 + lk * 4 + reg;
            int pxg = (y0 + (p >> 3)) * 64 + x0 + (p & 7);
#pragma unroll
            for (int nr = 0; nr < 4; ++nr)
                acc[mr][nr][reg] += (float)zxb[pxg * 256 + w * 64 + nr * 16 + l15];
        }
    // last K-iter ended with __syncthreads(): all LDS reads complete
#pragma unroll
    for (int mr = 0; mr < 4; ++mr)
#pragma unroll
        for (int reg = 0; reg < 4; ++reg) {
            int p = mr * 16 + lk * 4 + reg;
#pragma unroll
            for (int nr = 0; nr < 4; ++nr)
                zl[p * ZL_STRIDE + w * 64 + nr * 16 + l15] = acc[mr][nr][reg];
        }
    __syncthreads();

    // gates + BN + pool: thread = (row-pair rp, channel c)
    const int c  = tid & 63;
    const int rp = tid >> 6;
    const float scale = gamma[c] * rsqrtf(var[c] + BN_EPS);
    const float bns   = beta[c] - mean[c] * scale;
    f16* ho = hp_out + b * (66 * 66 * 64);

#pragma unroll
    for (int pc = 0; pc < 4; ++pc) {
        float m = -INFINITY;
#pragma unroll
        for (int dy = 0; dy < 2; ++dy)
#pragma unroll
            for (int dx = 0; dx < 2; ++dx) {
                int p  = (rp * 2 + dy) * 8 + pc * 2 + dx;
                float zi = zl[p * ZL_STRIDE + c];
                float zf = zl[p * ZL_STRIDE + 64 + c];
                float zg = zl[p * ZL_STRIDE + 128 + c];
                float zo = zl[p * ZL_STRIDE + 192 + c];
                int y  = y0 + rp * 2 + dy;
                int xg = x0 + pc * 2 + dx;
                int coff = ((b * 64 + y) * 64 + xg) * 64 + c;
                float gi = hsig(zi), gf = hsig(zf);
                float gg = tanhf(zg), go = hsig(zo);
                float cn = gf * c_st[coff] + gi * gg;
                c_st[coff] = cn;
                float h = go * tanhf(cn);
                ho[((b == b ? (y + 1) : 0) * 66 + xg + 1) * 64 + c] = (f16)h;
                m = fmaxf(m, h * scale + bns);
            }
        out[(((b * TT + t) * 32 + ty * 4 + rp) * 32 + tx * 4 + pc) * 64 + c] = m;
    }
}

// ---------------------------------------------------------------------------
extern "C" void kernel_launch(void* const* d_in, const int* in_sizes, int n_in,
                              void* d_out, int out_size, void* d_ws, size_t ws_size,
                              hipStream_t stream) {
    const float* x     = (const float*)d_in[0];
    const float* W     = (const float*)d_in[1];
    const float* U     = (const float*)d_in[2];
    const float* bias  = (const float*)d_in[3];
    const float* gamma = (const float*)d_in[4];
    const float* beta  = (const float*)d_in[5];
    const float* mean  = (const float*)d_in[6];
    const float* var   = (const float*)d_in[7];

    float* out = (float*)d_out;
    char*  ws  = (char*)d_ws;
    f16*   hp0 = (f16*)ws;
    f16*   hp1 = (f16*)(ws + OFF_HP1);
    float* cst = (float*)(ws + OFF_CST);
    f16*   x16 = (f16*)(ws + OFF_X16);
    f16*   wtx = (f16*)(ws + OFF_WTX);
    f16*   wth = (f16*)(ws + OFF_WTH);
    f16*   zx  = (f16*)(ws + OFF_ZX);

    // zero h buffers (borders!) + c_state
    hipMemsetAsync(d_ws, 0, (size_t)(OFF_CST + CST_BYTES), stream);
    prep_wt_kernel<<<dim3(576), dim3(256), 0, stream>>>(W, U, wtx, wth);
    convert_x_kernel<<<dim3(8192), dim3(256), 0, stream>>>(x, x16);
    zx_gemm<<<dim3(4096), dim3(256), 0, stream>>>(x16, wtx, bias, zx);

    for (int t = 0; t < TT; ++t) {
        const f16* hin = (t & 1) ? hp1 : hp0;
        f16*       hou = (t & 1) ? hp0 : hp1;
        step_fused<<<dim3(256), dim3(256), 0, stream>>>(
            hin, hou, wth, zx, cst, out, gamma, beta, mean, var, t);
    }
}